// Round 3
// baseline (175.669 us; speedup 1.0000x reference)
//
#include <hip/hip_runtime.h>
#include <hip/hip_cooperative_groups.h>
#include <math.h>

namespace cg = cooperative_groups;

// ws layout (floats):
//   terms: [0, 6144)    512*12: {-Lr, Li, t0r,t0i, t1r,t1i, t2r,t2i, t3r,t3i, Lr^2, t2s}
//   ZT:    [8192, +131072)  single plane of 65536 float2: ZT[t1*256 + l1]
constexpr int WS_TERMS = 0;
constexpr int WS_ZT    = 8192;

__device__ __forceinline__ float sin2pi(float x) { return __builtin_amdgcn_sinf(x); }
__device__ __forceinline__ float cos2pi(float x) { return __builtin_amdgcn_cosf(x); }

// ---------------------------------------------------------------------------
// Single fused cooperative kernel.  256 blocks x 512 threads (1 block/CU).
// Rationale: rounds 0-2 showed our 3 kernels sum to ~25us of real work while
// dur_us sits at ~105us dominated by harness poison fills + per-dispatch
// overhead.  The only lever we own is dispatch count: 3 launches + 2 kernel
// boundaries -> 1 launch + 2 grid.sync().
//
// Phase 0 (setup): block b computes terms rows n=2b, 2b+1 (half-block each).
// Phase 1 (mainA): block b = l1; thread (u=tid&63, chunk=tid>>6) covers FOUR
//   l2 in {u, u+64, u+128, u+192} x 64 n.  Writes one summed ZT plane.
// Phase 2 (fftB):  block b = t1; 256 outputs t2, 4-way j-split, 2 reps.
// LDS: terms[6144] | planes[4][64][9]=2304 @6144 | red[64][9]=576 @8448
//      xrow float2[64] @0 | partA float2[512] @128 | ph2: zrow@0, partB@512
__global__ __launch_bounds__(512) void k_fused(
    const float* __restrict__ Lr, const float* __restrict__ Li,
    const float* __restrict__ pr, const float* __restrict__ pi,
    const float* __restrict__ qr, const float* __restrict__ qi,
    const float* __restrict__ Vr, const float* __restrict__ Vi,
    const float* __restrict__ Ct, const float* __restrict__ Bv,
    const float* __restrict__ log_step,
    float* __restrict__ terms, float* __restrict__ ZTf, float* __restrict__ out)
{
    __shared__ float buf[9024];   // 36.1 KB -> 1 block/CU
    cg::grid_group grid = cg::this_grid();
    int tid = threadIdx.x;
    int b   = blockIdx.x;

    // ===================== Phase 0: setup (2 n per block) ==================
    {
        int half = tid >> 8;           // 0..1
        int t    = tid & 255;
        int n    = 2*b + half;
        float b0 = Bv[t], b1 = Bv[t + 256];
        float sr = fmaf(Vr[n*512 + t], b0, Vr[n*512 + t + 256] * b1);
        float si = fmaf(Vi[n*512 + t], b0, Vi[n*512 + t + 256] * b1);
        #pragma unroll
        for (int off = 32; off > 0; off >>= 1) {
            sr += __shfl_down(sr, off, 64);
            si += __shfl_down(si, off, 64);
        }
        if ((t & 63) == 0) {           // lane 0 of each of this half's 4 waves
            buf[half*8 + (t >> 6)*2]     = sr;
            buf[half*8 + (t >> 6)*2 + 1] = si;
        }
        __syncthreads();
        if (t == 0) {                  // tid==0 (n=2b) and tid==256 (n=2b+1)
            const float* rd = buf + half*8;
            float b0r = rd[0] + rd[2] + rd[4] + rd[6];
            float b0i = rd[1] + rd[3] + rd[5] + rd[7];
            double step = exp((double)log_step[0]);
            float t2s = (float)(2.0 / step);
            float lr  = Lr[n];
            float a0r = Ct[2*n], a0i = -Ct[2*n+1];   // conj(Ct_c)
            float a1r = qr[n],   a1i = -qi[n];       // conj(q)
            float b1r = pr[n],   b1i = pi[n];        // p
            float* tm = terms + n * 12;
            tm[0]  = -lr;                 tm[1]  = Li[n];
            tm[2]  = a0r*b0r - a0i*b0i;   tm[3]  = a0r*b0i + a0i*b0r;
            tm[4]  = a0r*b1r - a0i*b1i;   tm[5]  = a0r*b1i + a0i*b1r;
            tm[6]  = a1r*b0r - a1i*b0i;   tm[7]  = a1r*b0i + a1i*b0r;
            tm[8]  = a1r*b1r - a1i*b1i;   tm[9]  = a1r*b1i + a1i*b1r;
            tm[10] = lr*lr;               tm[11] = t2s;
        }
    }
    grid.sync();   // terms visible grid-wide

    // ===================== Phase 1: Cauchy + stage-A DFT ===================
    {
        int l1 = b;

        // stage terms -> LDS (1536 float4, 3 per thread, coalesced)
        {
            float4* dst = (float4*)buf;
            const float4* src = (const float4*)terms;
            #pragma unroll
            for (int i = 0; i < 3; ++i) dst[tid + 512*i] = src[tid + 512*i];
        }

        int u     = tid & 63;
        int chunk = tid >> 6;              // wave-uniform

        float t2s = terms[11];             // uniform global load

        float T[4], g_i[4];
        #pragma unroll
        for (int q = 0; q < 4; ++q) {
            int l = l1 + 256*(u + 64*q);
            float tv2 = (float)l * (1.0f / 131072.0f);   // exact fp32 fraction
            float sn  = sin2pi(tv2), cn = cos2pi(tv2);
            float Tq  = sn / cn;                          // tan(pi*l/L)
            float gq  = t2s * Tq;
            // pole l = L/2: legit |T| <= ~2.1e4; bigger is the pole -> r=0
            if (!(fabsf(Tq) <= 1.0e6f)) { gq = 3e30f; Tq = 0.f; }
            T[q] = Tq; g_i[q] = gq;
        }
        __syncthreads();                              // staging visible

        float ac[4][8];
        #pragma unroll
        for (int q = 0; q < 4; ++q)
            #pragma unroll
            for (int c = 0; c < 8; ++c) ac[q][c] = 0.f;

        const float4* t4 = (const float4*)buf + chunk * 64 * 3;
        #pragma unroll 2
        for (int n = 0; n < 64; ++n) {
            float4 Aq = t4[n*3 + 0];   // -Lr, Li, t0r, t0i  (broadcast b128)
            float4 Bq = t4[n*3 + 1];   // t1r, t1i, t2r, t2i
            float4 Cq = t4[n*3 + 2];   // t3r, t3i, Lr^2, t2s
            #pragma unroll
            for (int q = 0; q < 4; ++q) {
                float di = g_i[q] - Aq.y;
                float dd = fmaf(di, di, Cq.z);       // di^2 + Lr^2
                float iv = __builtin_amdgcn_rcpf(dd);
                float rr = Aq.x * iv;                // (-Lr)/dd
                float ri = -di * iv;
                ac[q][0] = fmaf(rr, Aq.z, ac[q][0]); ac[q][0] = fmaf(-ri, Aq.w, ac[q][0]);
                ac[q][1] = fmaf(rr, Aq.w, ac[q][1]); ac[q][1] = fmaf( ri, Aq.z, ac[q][1]);
                ac[q][2] = fmaf(rr, Bq.x, ac[q][2]); ac[q][2] = fmaf(-ri, Bq.y, ac[q][2]);
                ac[q][3] = fmaf(rr, Bq.y, ac[q][3]); ac[q][3] = fmaf( ri, Bq.x, ac[q][3]);
                ac[q][4] = fmaf(rr, Bq.z, ac[q][4]); ac[q][4] = fmaf(-ri, Bq.w, ac[q][4]);
                ac[q][5] = fmaf(rr, Bq.w, ac[q][5]); ac[q][5] = fmaf( ri, Bq.z, ac[q][5]);
                ac[q][6] = fmaf(rr, Cq.x, ac[q][6]); ac[q][6] = fmaf(-ri, Cq.y, ac[q][6]);
                ac[q][7] = fmaf(rr, Cq.y, ac[q][7]); ac[q][7] = fmaf( ri, Cq.x, ac[q][7]);
            }
        }
        __syncthreads();   // terms reads done; LDS reusable

        float accR = 0.f, accI = 0.f;     // per-(t1=tid<256) sum over quarters

        #pragma unroll
        for (int q = 0; q < 4; ++q) {
            // fold 8 n-chunks -> 4 planes
            if (chunk >= 4) {
                float* p = buf + 6144 + (chunk - 4) * 576 + u * 9;
                #pragma unroll
                for (int c = 0; c < 8; ++c) p[c] = ac[q][c];
            }
            __syncthreads();
            if (chunk < 4) {
                float* p = buf + 6144 + chunk * 576 + u * 9;
                #pragma unroll
                for (int c = 0; c < 8; ++c) p[c] += ac[q][c];
            }
            __syncthreads();

            // stage-1: 512 slots -> red @8448
            {
                int a = (tid >> 3) * 9 + (tid & 7);
                buf[8448 + a] = buf[6144 + a] + buf[6720 + a] + buf[7296 + a] + buf[7872 + a];
            }
            __syncthreads();

            // stage-2: atRoots for l2 = 64q + tid (tid<64); own T[q]
            if (tid < 64) {
                const float* rd = buf + 8448 + tid * 9;
                float s0r = rd[0], s0i = rd[1], s1r = rd[2], s1i = rd[3];
                float s2r = rd[4], s2i = rd[5], s3r = rd[6], s3i = rd[7];
                float e1r = 1.f + s3r, e1i = s3i;
                float eiv = 1.0f / fmaf(e1r, e1r, e1i * e1i);
                float m_r = s1r * s2r - s1i * s2i;
                float m_i = s1r * s2i + s1i * s2r;
                float q_r = (m_r * e1r + m_i * e1i) * eiv;
                float q_i = (m_i * e1r - m_r * e1i) * eiv;
                float u_r = s0r - q_r;
                float u_i = s0i - q_i;
                float Tq  = T[q];
                ((float2*)buf)[tid] = make_float2(u_r - Tq * u_i, u_i + Tq * u_r);
            }
            __syncthreads();

            // partial DFT-A over this quarter's 64 l2 (2-way split)
            {
                int t1 = tid & 255;
                int s  = tid >> 8;            // 0..1, wave-uniform
                int j0 = s * 32;
                int mm0 = ((q*64 + j0) * t1) & 255;
                float curR = cos2pi((float)mm0 * (1.0f/256.0f));
                float curI = sin2pi((float)mm0 * (1.0f/256.0f));
                float rotR = cos2pi((float)t1 * (1.0f/256.0f));
                float rotI = sin2pi((float)t1 * (1.0f/256.0f));
                const float2* xrow = (const float2*)buf;
                float yr = 0.f, yi = 0.f;
                #pragma unroll 8
                for (int j = j0; j < j0 + 32; ++j) {
                    float2 x = xrow[j];   // broadcast
                    yr = fmaf(x.x, curR, yr); yr = fmaf(-x.y, curI, yr);
                    yi = fmaf(x.x, curI, yi); yi = fmaf( x.y, curR, yi);
                    float nR = curR * rotR - curI * rotI;
                    float nI = curR * rotI + curI * rotR;
                    curR = nR; curI = nI;
                }
                ((float2*)(buf + 128))[tid] = make_float2(yr, yi);   // partA @128
            }
            __syncthreads();
            if (tid < 256) {
                const float2* pA = (const float2*)(buf + 128);
                float2 p0 = pA[tid], p1 = pA[tid + 256];
                accR += p0.x + p1.x;
                accI += p0.y + p1.y;
            }
            // next q's fold writes @6144+ (disjoint from partA @128..1152);
            // separated from stage-1 plane reads by >=2 barriers.
        }

        // W_L twiddle + single summed plane write
        if (tid < 256) {
            int mm = (l1 * tid) & 65535;
            float tv = (float)mm * (1.0f / 65536.0f);
            float twR = cos2pi(tv), twI = sin2pi(tv);
            ((float2*)ZTf)[tid * 256 + l1] =
                make_float2(accR * twR - accI * twI, accR * twI + accI * twR);
        }
    }
    grid.sync();   // ZT visible grid-wide

    // ===================== Phase 2: DFT-B (block = t1) =====================
    {
        int t1 = b;
        if (tid < 256)
            ((float2*)buf)[tid] = ((const float2*)ZTf)[t1 * 256 + tid];
        __syncthreads();
        int tl = tid & 127;
        int s  = tid >> 7;            // 0..3, wave-uniform
        const float2* zrow = (const float2*)buf;
        #pragma unroll
        for (int rep = 0; rep < 2; ++rep) {
            int t2 = rep*128 + tl;
            int m0 = (s * t2) & 3;    // phasor W_256^{s*64*t2} = i^{s*t2} (exact)
            float curR = (m0 == 0) ? 1.f : (m0 == 2 ? -1.f : 0.f);
            float curI = (m0 == 1) ? 1.f : (m0 == 3 ? -1.f : 0.f);
            float rotR = cos2pi((float)t2 * (1.0f / 256.0f));
            float rotI = sin2pi((float)t2 * (1.0f / 256.0f));
            float o = 0.f;
            #pragma unroll 8
            for (int j = s * 64; j < s * 64 + 64; ++j) {
                float2 z = zrow[j];   // broadcast
                o = fmaf(z.x, curR, o);
                o = fmaf(-z.y, curI, o);
                float nR = curR * rotR - curI * rotI;
                float nI = curR * rotI + curI * rotR;
                curR = nR; curI = nI;
            }
            buf[512 + s*128 + tl] = o;
            __syncthreads();
            if (tid < 128) {
                float sum = buf[512+tid] + buf[640+tid] + buf[768+tid] + buf[896+tid];
                out[t1 + 256 * t2] = sum * (1.0f / 65536.0f);
            }
            __syncthreads();          // partB slots reusable for rep 1
        }
    }
}

// ---------------------------------------------------------------------------
extern "C" void kernel_launch(void* const* d_in, const int* in_sizes, int n_in,
                              void* d_out, int out_size, void* d_ws, size_t ws_size,
                              hipStream_t stream)
{
    const float* Lambda_re = (const float*)d_in[0];
    const float* Lambda_im = (const float*)d_in[1];
    const float* p_re      = (const float*)d_in[2];
    const float* p_im      = (const float*)d_in[3];
    const float* q_re      = (const float*)d_in[4];
    const float* q_im      = (const float*)d_in[5];
    const float* Vc_re     = (const float*)d_in[6];
    const float* Vc_im     = (const float*)d_in[7];
    const float* Ct        = (const float*)d_in[8];
    const float* Bv        = (const float*)d_in[9];
    const float* log_step  = (const float*)d_in[10];

    float* wsf   = (float*)d_ws;
    float* terms = wsf + WS_TERMS;
    float* ZT    = wsf + WS_ZT;
    float* outp  = (float*)d_out;

    void* args[] = {
        (void*)&Lambda_re, (void*)&Lambda_im,
        (void*)&p_re, (void*)&p_im, (void*)&q_re, (void*)&q_im,
        (void*)&Vc_re, (void*)&Vc_im, (void*)&Ct, (void*)&Bv, (void*)&log_step,
        (void*)&terms, (void*)&ZT, (void*)&outp
    };
    hipLaunchCooperativeKernel((const void*)k_fused, dim3(256), dim3(512),
                               args, 0, stream);
}

// Round 4
// 112.660 us; speedup vs baseline: 1.5593x; 1.5593x over previous
//
#include <hip/hip_runtime.h>
#include <math.h>

typedef float v2f __attribute__((ext_vector_type(2)));

// ws layout (floats):
//   terms: [0, 6144)    512*12: {-Lr, Li, t0r,t0i, t1r,t1i, t2r,t2i, t3r,t3i, Lr^2, t2s}
//   ZT:    [8192, +2*131072)  2 half-planes of 65536 float2: ZT[h][t1*256 + l1]
constexpr int WS_TERMS = 0;
constexpr int WS_ZT    = 8192;

__device__ __forceinline__ float sin2pi(float x) { return __builtin_amdgcn_sinf(x); }
__device__ __forceinline__ float cos2pi(float x) { return __builtin_amdgcn_cosf(x); }

// ---------------------------------------------------------------------------
// Kernel 1: per-n setup.  Bc = Vc @ B (complex); terms in r12 format.
__global__ __launch_bounds__(256) void k_setup(
    const float* __restrict__ Lr, const float* __restrict__ Li,
    const float* __restrict__ pr, const float* __restrict__ pi,
    const float* __restrict__ qr, const float* __restrict__ qi,
    const float* __restrict__ Vr, const float* __restrict__ Vi,
    const float* __restrict__ Ct, const float* __restrict__ Bv,
    const float* __restrict__ log_step,
    float* __restrict__ terms)
{
    __shared__ float red[8];
    int n = blockIdx.x;
    int t = threadIdx.x;
    float b0 = Bv[t], b1 = Bv[t + 256];
    float sr = fmaf(Vr[n*512 + t], b0, Vr[n*512 + t + 256] * b1);
    float si = fmaf(Vi[n*512 + t], b0, Vi[n*512 + t + 256] * b1);
    #pragma unroll
    for (int off = 32; off > 0; off >>= 1) {
        sr += __shfl_down(sr, off, 64);
        si += __shfl_down(si, off, 64);
    }
    if ((t & 63) == 0) { red[(t >> 6)*2] = sr; red[(t >> 6)*2 + 1] = si; }
    __syncthreads();
    if (t == 0) {
        float b0r = red[0] + red[2] + red[4] + red[6];
        float b0i = red[1] + red[3] + red[5] + red[7];
        double step = exp((double)log_step[0]);
        float t2s = (float)(2.0 / step);
        float lr  = Lr[n];
        float a0r = Ct[2*n], a0i = -Ct[2*n+1];   // conj(Ct_c)
        float a1r = qr[n],   a1i = -qi[n];       // conj(q)
        float b1r = pr[n],   b1i = pi[n];        // p
        float* tm = terms + n * 12;
        tm[0]  = -lr;                 tm[1]  = Li[n];
        tm[2]  = a0r*b0r - a0i*b0i;   tm[3]  = a0r*b0i + a0i*b0r;
        tm[4]  = a0r*b1r - a0i*b1i;   tm[5]  = a0r*b1i + a0i*b1r;
        tm[6]  = a1r*b0r - a1i*b0i;   tm[7]  = a1r*b0i + a1i*b0r;
        tm[8]  = a1r*b1r - a1i*b1i;   tm[9]  = a1r*b1i + a1i*b1r;
        tm[10] = lr*lr;               tm[11] = t2s;
    }
}

// ---------------------------------------------------------------------------
// Kernel 2: Cauchy + resolvent + partial stage-A DFT.
// 512 blocks x 512 threads; block = (l1 = b>>1, h = b&1) covers l2 in
// [h*128, h*128+128).  Thread (u = tid&63, chunk = tid>>6): TWO l2 values
// {h*128+u, h*128+64+u} packed into v2f lanes so the Cauchy MACs use
// v_pk_fma_f32 (2 fp32 FMA/lane/cyc): 16 scalar fma -> 8 pk_fma, and
// di/dd/rr/ri pack too.  2 blocks/CU = 16 waves/CU (4/SIMD) keeps latency
// hiding (round-2's 1 block/CU at 2/SIMD regressed).  Each block sums its
// two quarters in registers and writes one of 2 ZT half-planes.
// VALU-floor arithmetic: 7.05e8 lane-ops at 1/lane/cyc = 9us chip-wide;
// packed path targets ~5.5-7us.
// LDS overlay: xrow float2[64] @0 | partA float2[512] @128 |
//              planes[4][64][9]=2304 @1280 | red[64][9]=576 @3584
__global__ __launch_bounds__(512) void k_mainA(
    const float* __restrict__ terms,
    float* __restrict__ ZTf)
{
    __shared__ float buf[4160];   // 16.64 KB
    int tid = threadIdx.x;
    int b   = blockIdx.x;
    int l1  = b >> 1;
    int h   = b & 1;

    int u     = tid & 63;
    int chunk = tid >> 6;              // wave-uniform

    float t2s = terms[11];             // uniform load

    float T0, T1, g0, g1;
    {
        int l = l1 + 256*(h*128 + u);
        float tv2 = (float)l * (1.0f / 131072.0f);   // exact fp32 fraction
        float sn = sin2pi(tv2), cn = cos2pi(tv2);
        float Tq = sn / cn;                           // tan(pi*l/L)
        float gq = t2s * Tq;
        // pole l = L/2: legit |T| <= ~2.1e4; bigger is the pole -> r=0
        if (!(fabsf(Tq) <= 1.0e6f)) { gq = 3e30f; Tq = 0.f; }
        T0 = Tq; g0 = gq;
    }
    {
        int l = l1 + 256*(h*128 + 64 + u);
        float tv2 = (float)l * (1.0f / 131072.0f);
        float sn = sin2pi(tv2), cn = cos2pi(tv2);
        float Tq = sn / cn;
        float gq = t2s * Tq;
        if (!(fabsf(Tq) <= 1.0e6f)) { gq = 3e30f; Tq = 0.f; }
        T1 = Tq; g1 = gq;
    }

    v2f g2 = {g0, g1};
    v2f acr0 = {0.f,0.f}, acr1 = {0.f,0.f}, acr2 = {0.f,0.f}, acr3 = {0.f,0.f};
    v2f aci0 = {0.f,0.f}, aci1 = {0.f,0.f}, aci2 = {0.f,0.f}, aci3 = {0.f,0.f};

    const float4* t4 = (const float4*)terms + chunk * 64 * 3;
    #pragma unroll 4
    for (int n = 0; n < 64; ++n) {
        float4 Aq = t4[n*3 + 0];   // -Lr, Li, t0r, t0i
        float4 Bq = t4[n*3 + 1];   // t1r, t1i, t2r, t2i
        float4 Cq = t4[n*3 + 2];   // t3r, t3i, Lr^2, t2s
        v2f di = g2 - (v2f){Aq.y, Aq.y};
        v2f dd = __builtin_elementwise_fma(di, di, (v2f){Cq.z, Cq.z});
        v2f iv = {__builtin_amdgcn_rcpf(dd.x), __builtin_amdgcn_rcpf(dd.y)};
        v2f rr  = (v2f){Aq.x, Aq.x} * iv;   // (-Lr)/dd per lane
        v2f mri = di * iv;                  // = -ri  (ri = -di/dd)
        // re += rr*tr + mri*ti ;  im += rr*ti - mri*tr
        acr0 = __builtin_elementwise_fma(rr,   (v2f){Aq.z, Aq.z}, acr0);
        acr0 = __builtin_elementwise_fma(mri,  (v2f){Aq.w, Aq.w}, acr0);
        aci0 = __builtin_elementwise_fma(rr,   (v2f){Aq.w, Aq.w}, aci0);
        aci0 = __builtin_elementwise_fma(-mri, (v2f){Aq.z, Aq.z}, aci0);
        acr1 = __builtin_elementwise_fma(rr,   (v2f){Bq.x, Bq.x}, acr1);
        acr1 = __builtin_elementwise_fma(mri,  (v2f){Bq.y, Bq.y}, acr1);
        aci1 = __builtin_elementwise_fma(rr,   (v2f){Bq.y, Bq.y}, aci1);
        aci1 = __builtin_elementwise_fma(-mri, (v2f){Bq.x, Bq.x}, aci1);
        acr2 = __builtin_elementwise_fma(rr,   (v2f){Bq.z, Bq.z}, acr2);
        acr2 = __builtin_elementwise_fma(mri,  (v2f){Bq.w, Bq.w}, acr2);
        aci2 = __builtin_elementwise_fma(rr,   (v2f){Bq.w, Bq.w}, aci2);
        aci2 = __builtin_elementwise_fma(-mri, (v2f){Bq.z, Bq.z}, aci2);
        acr3 = __builtin_elementwise_fma(rr,   (v2f){Cq.x, Cq.x}, acr3);
        acr3 = __builtin_elementwise_fma(mri,  (v2f){Cq.y, Cq.y}, acr3);
        aci3 = __builtin_elementwise_fma(rr,   (v2f){Cq.y, Cq.y}, aci3);
        aci3 = __builtin_elementwise_fma(-mri, (v2f){Cq.x, Cq.x}, aci3);
    }

    float accR = 0.f, accI = 0.f;     // per-(t1=tid<256) sum over this block's 2 quarters

    #pragma unroll
    for (int j = 0; j < 2; ++j) {
        float av[8];
        if (j == 0) {
            av[0]=acr0.x; av[1]=aci0.x; av[2]=acr1.x; av[3]=aci1.x;
            av[4]=acr2.x; av[5]=aci2.x; av[6]=acr3.x; av[7]=aci3.x;
        } else {
            av[0]=acr0.y; av[1]=aci0.y; av[2]=acr1.y; av[3]=aci1.y;
            av[4]=acr2.y; av[5]=aci2.y; av[6]=acr3.y; av[7]=aci3.y;
        }
        // ---- fold 8 n-chunks -> 4 planes @1280 (chunks 4..7 write, 0..3 add)
        if (chunk >= 4) {
            float* p = buf + 1280 + (chunk - 4) * 576 + u * 9;
            #pragma unroll
            for (int c = 0; c < 8; ++c) p[c] = av[c];
        }
        __syncthreads();
        if (chunk < 4) {
            float* p = buf + 1280 + chunk * 576 + u * 9;
            #pragma unroll
            for (int c = 0; c < 8; ++c) p[c] += av[c];
        }
        __syncthreads();

        // ---- stage-1: 512 slots (64 l2-local x 8 comp) -> red @3584
        {
            int a = (tid >> 3) * 9 + (tid & 7);
            buf[3584 + a] = buf[1280 + a] + buf[1856 + a] + buf[2432 + a] + buf[3008 + a];
        }
        __syncthreads();

        // ---- stage-2: atRoots for l2 = (2h+j)*64 + tid (tid<64); own T (u=tid, chunk=0)
        if (tid < 64) {
            const float* rd = buf + 3584 + tid * 9;
            float s0r = rd[0], s0i = rd[1], s1r = rd[2], s1i = rd[3];
            float s2r = rd[4], s2i = rd[5], s3r = rd[6], s3i = rd[7];
            float e1r = 1.f + s3r, e1i = s3i;
            float eiv = 1.0f / fmaf(e1r, e1r, e1i * e1i);
            float m_r = s1r * s2r - s1i * s2i;
            float m_i = s1r * s2i + s1i * s2r;
            float q_r = (m_r * e1r + m_i * e1i) * eiv;
            float q_i = (m_i * e1r - m_r * e1i) * eiv;
            float u_r = s0r - q_r;
            float u_i = s0i - q_i;
            float Tq  = (j == 0) ? T0 : T1;
            ((float2*)buf)[tid] = make_float2(u_r - Tq * u_i, u_i + Tq * u_r); // xrow @0
        }
        __syncthreads();

        // ---- partial DFT-A over this quarter's 64 l2 (2-way split)
        {
            int t1 = tid & 255;
            int s  = tid >> 8;            // 0..1, wave-uniform
            int j0 = s * 32;
            int Q  = 2*h + j;
            int mm0 = ((Q*64 + j0) * t1) & 255;
            float curR = cos2pi((float)mm0 * (1.0f/256.0f));
            float curI = sin2pi((float)mm0 * (1.0f/256.0f));
            float rotR = cos2pi((float)t1 * (1.0f/256.0f));
            float rotI = sin2pi((float)t1 * (1.0f/256.0f));
            const float2* xrow = (const float2*)buf;
            float yr = 0.f, yi = 0.f;
            #pragma unroll 8
            for (int jj = j0; jj < j0 + 32; ++jj) {
                float2 x = xrow[jj];   // broadcast
                yr = fmaf(x.x, curR, yr); yr = fmaf(-x.y, curI, yr);
                yi = fmaf(x.x, curI, yi); yi = fmaf( x.y, curR, yi);
                float nR = curR * rotR - curI * rotI;
                float nI = curR * rotI + curI * rotR;
                curR = nR; curI = nI;
            }
            ((float2*)(buf + 128))[tid] = make_float2(yr, yi);   // partA @128
        }
        __syncthreads();
        if (tid < 256) {
            const float2* pA = (const float2*)(buf + 128);
            float2 p0 = pA[tid], p1 = pA[tid + 256];
            accR += p0.x + p1.x;
            accI += p0.y + p1.y;
        }
        // next j's fold writes planes @1280+ (disjoint from partA @128..1152);
        // partA re-write is 4 barriers away -> no extra barrier needed.
    }

    // ---- W_L twiddle + half-plane write
    if (tid < 256) {
        int mm = (l1 * tid) & 65535;
        float tv = (float)mm * (1.0f / 65536.0f);
        float twR = cos2pi(tv), twI = sin2pi(tv);
        ((float2*)(ZTf + h * 131072))[tid * 256 + l1] =
            make_float2(accR * twR - accI * twI, accR * twI + accI * twR);
    }
}

// ---------------------------------------------------------------------------
// Kernel 3: DFT-B.  1024 blocks x 256 threads; block = (t1 = b>>2, qT = b&3)
// covers t2 in [qT*64, qT*64+64).  zrow = sum of 2 ZT half-planes.
__global__ __launch_bounds__(256) void k_fftB(
    const float* __restrict__ ZTf, float* __restrict__ out)
{
    __shared__ float buf2[768];    // zrow float2[256] @0, partB[256] @512
    int tid = threadIdx.x;
    int b   = blockIdx.x;
    int t1 = b >> 2;
    int qT = b & 3;
    {
        float2 z = make_float2(0.f, 0.f);
        #pragma unroll
        for (int q = 0; q < 2; ++q) {
            float2 v = ((const float2*)(ZTf + q * 131072))[t1 * 256 + tid];
            z.x += v.x; z.y += v.y;
        }
        ((float2*)buf2)[tid] = z;
    }
    int k2 = tid & 63;
    int s  = tid >> 6;            // 0..3, wave-uniform
    int t2 = qT * 64 + k2;
    int m0 = (s * t2) & 3;
    float curR = (m0 == 0) ? 1.f : (m0 == 2 ? -1.f : 0.f);
    float curI = (m0 == 1) ? 1.f : (m0 == 3 ? -1.f : 0.f);
    float rotR = cos2pi((float)t2 * (1.0f / 256.0f));
    float rotI = sin2pi((float)t2 * (1.0f / 256.0f));
    __syncthreads();
    const float2* zrow = (const float2*)buf2;
    float o = 0.f;
    #pragma unroll 8
    for (int j = s * 64; j < s * 64 + 64; ++j) {
        float2 z = zrow[j];   // broadcast
        o = fmaf(z.x, curR, o);
        o = fmaf(-z.y, curI, o);
        float nR = curR * rotR - curI * rotI;
        float nI = curR * rotI + curI * rotR;
        curR = nR; curI = nI;
    }
    buf2[512 + tid] = o;
    __syncthreads();
    if (tid < 64) {
        float sum = buf2[512+tid] + buf2[512+tid+64] + buf2[512+tid+128] + buf2[512+tid+192];
        out[t1 + 256 * (qT * 64 + tid)] = sum * (1.0f / 65536.0f);
    }
}

// ---------------------------------------------------------------------------
extern "C" void kernel_launch(void* const* d_in, const int* in_sizes, int n_in,
                              void* d_out, int out_size, void* d_ws, size_t ws_size,
                              hipStream_t stream)
{
    const float* Lambda_re = (const float*)d_in[0];
    const float* Lambda_im = (const float*)d_in[1];
    const float* p_re      = (const float*)d_in[2];
    const float* p_im      = (const float*)d_in[3];
    const float* q_re      = (const float*)d_in[4];
    const float* q_im      = (const float*)d_in[5];
    const float* Vc_re     = (const float*)d_in[6];
    const float* Vc_im     = (const float*)d_in[7];
    const float* Ct        = (const float*)d_in[8];
    const float* Bv        = (const float*)d_in[9];
    const float* log_step  = (const float*)d_in[10];

    float* wsf   = (float*)d_ws;
    float* terms = wsf + WS_TERMS;
    float* ZT    = wsf + WS_ZT;
    float* outp  = (float*)d_out;

    k_setup<<<512, 256, 0, stream>>>(Lambda_re, Lambda_im, p_re, p_im, q_re, q_im,
                                     Vc_re, Vc_im, Ct, Bv, log_step, terms);
    k_mainA<<<512, 512, 0, stream>>>(terms, ZT);
    k_fftB<<<1024, 256, 0, stream>>>(ZT, outp);
}

// Round 5
// 105.971 us; speedup vs baseline: 1.6577x; 1.0631x over previous
//
#include <hip/hip_runtime.h>
#include <math.h>

// ws layout (floats):
//   terms: [0, 8192)    512*16: {-Lr, Li, t0r,t0i, t1r,t1i, t2r,t2i, t3r,t3i, Lr^2, t2s, pad*4}
//          rows padded to 16 floats (64 B) so wave-uniform s_load merges cleanly.
//   ZTp:   [8192, +4*131072)  4 planes of 65536 float2: ZTp[q][t1*256 + l1]
constexpr int WS_TERMS = 0;
constexpr int WS_ZT    = 8192;

__device__ __forceinline__ float sin2pi(float x) { return __builtin_amdgcn_sinf(x); }
__device__ __forceinline__ float cos2pi(float x) { return __builtin_amdgcn_cosf(x); }

// ---------------------------------------------------------------------------
// Kernel 1: per-n setup.  Bc = Vc @ B (complex); terms in r16 format.
__global__ __launch_bounds__(256) void k_setup(
    const float* __restrict__ Lr, const float* __restrict__ Li,
    const float* __restrict__ pr, const float* __restrict__ pi,
    const float* __restrict__ qr, const float* __restrict__ qi,
    const float* __restrict__ Vr, const float* __restrict__ Vi,
    const float* __restrict__ Ct, const float* __restrict__ Bv,
    const float* __restrict__ log_step,
    float* __restrict__ terms)
{
    __shared__ float red[8];
    int n = blockIdx.x;
    int t = threadIdx.x;
    float b0 = Bv[t], b1 = Bv[t + 256];
    float sr = fmaf(Vr[n*512 + t], b0, Vr[n*512 + t + 256] * b1);
    float si = fmaf(Vi[n*512 + t], b0, Vi[n*512 + t + 256] * b1);
    #pragma unroll
    for (int off = 32; off > 0; off >>= 1) {
        sr += __shfl_down(sr, off, 64);
        si += __shfl_down(si, off, 64);
    }
    if ((t & 63) == 0) { red[(t >> 6)*2] = sr; red[(t >> 6)*2 + 1] = si; }
    __syncthreads();
    if (t == 0) {
        float b0r = red[0] + red[2] + red[4] + red[6];
        float b0i = red[1] + red[3] + red[5] + red[7];
        double step = exp((double)log_step[0]);
        float t2s = (float)(2.0 / step);
        float lr  = Lr[n];
        float a0r = Ct[2*n], a0i = -Ct[2*n+1];   // conj(Ct_c)
        float a1r = qr[n],   a1i = -qi[n];       // conj(q)
        float b1r = pr[n],   b1i = pi[n];        // p
        float* tm = terms + n * 16;
        tm[0]  = -lr;                 tm[1]  = Li[n];
        tm[2]  = a0r*b0r - a0i*b0i;   tm[3]  = a0r*b0i + a0i*b0r;
        tm[4]  = a0r*b1r - a0i*b1i;   tm[5]  = a0r*b1i + a0i*b1r;
        tm[6]  = a1r*b0r - a1i*b0i;   tm[7]  = a1r*b0i + a1i*b0r;
        tm[8]  = a1r*b1r - a1i*b1i;   tm[9]  = a1r*b1i + a1i*b1r;
        tm[10] = lr*lr;               tm[11] = t2s;
        tm[12] = 0.f; tm[13] = 0.f; tm[14] = 0.f; tm[15] = 0.f;
    }
}

// ---------------------------------------------------------------------------
// Kernel 2: Cauchy + resolvent + partial DFT-A.
// 1024 blocks x 512 threads; block = (l1 = b>>2, quarter = b&3) covers
// l2 in [quarter*64, quarter*64+64).  Thread (u = tid&63, chunk = tid>>6 in [0,8)):
// one l2 = quarter*64+u, n in [chunk*64, chunk*64+64).
// Terms reads are wave-uniform; served from L1/L2 broadcast (measured: same
// cost as LDS broadcast within noise; k_mainA is at its VALU-issue floor
// ~9us chip-wide = 7.05e8 lane-FMAs / (1024 SIMD x 32 lane/cyc) @2.4GHz).
// LDS only for fold/reduce phases: 2880 floats = 11.52 KB.
// Analytic: g = i*t2s*tan(pi*l/L) (pure imaginary), c = 1 + i*tan(pi*l/L).
// LDS overlay: planes[4][64][9]=2304 + red[64][9]@2304 | xrow@0 + partA@128
__global__ __launch_bounds__(512, 8) void k_mainA(
    const float* __restrict__ terms,
    float* __restrict__ ZTf)
{
    __shared__ float buf[2880];   // 11.52 KB
    int tid = threadIdx.x;
    int b   = blockIdx.x;
    int l1      = b >> 2;
    int quarter = b & 3;

    int u     = tid & 63;
    int chunk = __builtin_amdgcn_readfirstlane(tid >> 6);   // wave-uniform, SGPR
    int l2    = quarter*64 + u;
    int l     = l1 + 256*l2;

    float tv2 = (float)l * (1.0f / 131072.0f);   // exact fp32 fraction
    float sn  = sin2pi(tv2), cn = cos2pi(tv2);
    float T   = sn / cn;                          // tan(pi*l/L)
    float t2s = terms[11];                        // uniform scalar load
    float g_i = t2s * T;
    // pole l = L/2: legit |T| <= ~2.1e4; anything bigger is the pole -> r=0, c~=1
    if (!(fabsf(T) <= 1.0e6f)) { g_i = 3e30f; T = 0.f; }

    float ac[8];
    #pragma unroll
    for (int c = 0; c < 8; ++c) ac[c] = 0.f;

    // uniform base: chunk is SGPR, n is a uniform induction variable
    const float4* t4 = (const float4*)terms + chunk * 64 * 4;
    #pragma unroll 4
    for (int n = 0; n < 64; ++n) {
        float4 Aq = t4[n*4 + 0];   // -Lr, Li, t0r, t0i
        float4 Bq = t4[n*4 + 1];   // t1r, t1i, t2r, t2i
        float4 Cq = t4[n*4 + 2];   // t3r, t3i, Lr^2, t2s
        float di = g_i - Aq.y;
        float dd = fmaf(di, di, Cq.z);           // di^2 + Lr^2; inf at pole -> r=0
        float iv = __builtin_amdgcn_rcpf(dd);
        float rr = Aq.x * iv;                    // (-Lr)/dd
        float ri = -di * iv;
        ac[0] = fmaf(rr, Aq.z, ac[0]); ac[0] = fmaf(-ri, Aq.w, ac[0]);
        ac[1] = fmaf(rr, Aq.w, ac[1]); ac[1] = fmaf( ri, Aq.z, ac[1]);
        ac[2] = fmaf(rr, Bq.x, ac[2]); ac[2] = fmaf(-ri, Bq.y, ac[2]);
        ac[3] = fmaf(rr, Bq.y, ac[3]); ac[3] = fmaf( ri, Bq.x, ac[3]);
        ac[4] = fmaf(rr, Bq.z, ac[4]); ac[4] = fmaf(-ri, Bq.w, ac[4]);
        ac[5] = fmaf(rr, Bq.w, ac[5]); ac[5] = fmaf( ri, Bq.z, ac[5]);
        ac[6] = fmaf(rr, Cq.x, ac[6]); ac[6] = fmaf(-ri, Cq.y, ac[6]);
        ac[7] = fmaf(rr, Cq.y, ac[7]); ac[7] = fmaf( ri, Cq.x, ac[7]);
    }

    // ---- fold 8 n-chunks -> 4 planes (chunks 4..7 write, 0..3 accumulate)
    // no barrier needed before the writes: nothing has touched LDS yet
    if (chunk >= 4) {
        float* p = buf + (chunk - 4) * 576 + u * 9;
        #pragma unroll
        for (int c = 0; c < 8; ++c) p[c] = ac[c];
    }
    __syncthreads();
    if (chunk < 4) {
        float* p = buf + chunk * 576 + u * 9;
        #pragma unroll
        for (int c = 0; c < 8; ++c) p[c] += ac[c];
    }
    __syncthreads();

    // ---- stage-1: 512 slots (64 l2 x 8 comp), one per thread -> red @2304
    {
        int a = (tid >> 3) * 9 + (tid & 7);
        buf[2304 + a] = buf[a] + buf[576 + a] + buf[1152 + a] + buf[1728 + a];
    }
    __syncthreads();

    // ---- stage-2: atRoots for local l2 = tid (tid<64); own T (u=tid, chunk=0)
    if (tid < 64) {
        const float* rd = buf + 2304 + tid * 9;
        float s0r = rd[0], s0i = rd[1], s1r = rd[2], s1i = rd[3];
        float s2r = rd[4], s2i = rd[5], s3r = rd[6], s3i = rd[7];
        float e1r = 1.f + s3r, e1i = s3i;
        float eiv = 1.0f / fmaf(e1r, e1r, e1i * e1i);
        float m_r = s1r * s2r - s1i * s2i;
        float m_i = s1r * s2i + s1i * s2r;
        float q_r = (m_r * e1r + m_i * e1i) * eiv;
        float q_i = (m_i * e1r - m_r * e1i) * eiv;
        float u_r = s0r - q_r;
        float u_i = s0i - q_i;
        ((float2*)buf)[tid] = make_float2(u_r - T * u_i, u_i + T * u_r);  // xrow @0
    }
    __syncthreads();

    // ---- partial DFT-A over this quarter's 64 l2 (2-way split) + W_L twiddle
    {
        int t1 = tid & 255;
        int s  = tid >> 8;            // 0..1, wave-uniform
        int j0 = s * 32;
        int mm0 = ((quarter*64 + j0) * t1) & 255;
        float curR = cos2pi((float)mm0 * (1.0f/256.0f));
        float curI = sin2pi((float)mm0 * (1.0f/256.0f));
        float rotR = cos2pi((float)t1 * (1.0f/256.0f));
        float rotI = sin2pi((float)t1 * (1.0f/256.0f));
        const float2* xrow = (const float2*)buf;
        float yr = 0.f, yi = 0.f;
        #pragma unroll 8
        for (int j = j0; j < j0 + 32; ++j) {
            float2 x = xrow[j];   // broadcast
            yr = fmaf(x.x, curR, yr); yr = fmaf(-x.y, curI, yr);
            yi = fmaf(x.x, curI, yi); yi = fmaf( x.y, curR, yi);
            float nR = curR * rotR - curI * rotI;
            float nI = curR * rotI + curI * rotR;
            curR = nR; curI = nI;
        }
        ((float2*)(buf + 128))[tid] = make_float2(yr, yi);   // partA @128
    }
    __syncthreads();
    if (tid < 256) {
        const float2* pA = (const float2*)(buf + 128);
        float2 p0 = pA[tid], p1 = pA[tid + 256];
        float Yr = p0.x + p1.x;
        float Yi = p0.y + p1.y;
        int mm = (l1 * tid) & 65535;
        float tv = (float)mm * (1.0f / 65536.0f);
        float twR = cos2pi(tv), twI = sin2pi(tv);
        ((float2*)(ZTf + quarter * 131072))[tid * 256 + l1] =
            make_float2(Yr * twR - Yi * twI, Yr * twI + Yi * twR);
    }
}

// ---------------------------------------------------------------------------
// Kernel 3: DFT-B.  1024 blocks x 256 threads; block = (t1 = b>>2, qT = b&3)
// covers t2 in [qT*64, qT*64+64).  zrow = sum of 4 ZT planes.
__global__ __launch_bounds__(256) void k_fftB(
    const float* __restrict__ ZTf, float* __restrict__ out)
{
    __shared__ float buf2[768];    // zrow float2[256] @0, partB[256] @512
    int tid = threadIdx.x;
    int b   = blockIdx.x;
    int t1 = b >> 2;
    int qT = b & 3;
    {
        float2 z = make_float2(0.f, 0.f);
        #pragma unroll
        for (int q = 0; q < 4; ++q) {
            float2 v = ((const float2*)(ZTf + q * 131072))[t1 * 256 + tid];
            z.x += v.x; z.y += v.y;
        }
        ((float2*)buf2)[tid] = z;
    }
    int k2 = tid & 63;
    int s  = tid >> 6;            // 0..3, wave-uniform
    int t2 = qT * 64 + k2;
    int m0 = (s * t2) & 3;
    float curR = (m0 == 0) ? 1.f : (m0 == 2 ? -1.f : 0.f);
    float curI = (m0 == 1) ? 1.f : (m0 == 3 ? -1.f : 0.f);
    float rotR = cos2pi((float)t2 * (1.0f / 256.0f));
    float rotI = sin2pi((float)t2 * (1.0f / 256.0f));
    __syncthreads();
    const float2* zrow = (const float2*)buf2;
    float o = 0.f;
    #pragma unroll 8
    for (int j = s * 64; j < s * 64 + 64; ++j) {
        float2 z = zrow[j];   // broadcast
        o = fmaf(z.x, curR, o);
        o = fmaf(-z.y, curI, o);
        float nR = curR * rotR - curI * rotI;
        float nI = curR * rotI + curI * rotR;
        curR = nR; curI = nI;
    }
    buf2[512 + tid] = o;
    __syncthreads();
    if (tid < 64) {
        float sum = buf2[512+tid] + buf2[512+tid+64] + buf2[512+tid+128] + buf2[512+tid+192];
        out[t1 + 256 * (qT * 64 + tid)] = sum * (1.0f / 65536.0f);
    }
}

// ---------------------------------------------------------------------------
extern "C" void kernel_launch(void* const* d_in, const int* in_sizes, int n_in,
                              void* d_out, int out_size, void* d_ws, size_t ws_size,
                              hipStream_t stream)
{
    const float* Lambda_re = (const float*)d_in[0];
    const float* Lambda_im = (const float*)d_in[1];
    const float* p_re      = (const float*)d_in[2];
    const float* p_im      = (const float*)d_in[3];
    const float* q_re      = (const float*)d_in[4];
    const float* q_im      = (const float*)d_in[5];
    const float* Vc_re     = (const float*)d_in[6];
    const float* Vc_im     = (const float*)d_in[7];
    const float* Ct        = (const float*)d_in[8];
    const float* Bv        = (const float*)d_in[9];
    const float* log_step  = (const float*)d_in[10];

    float* wsf   = (float*)d_ws;
    float* terms = wsf + WS_TERMS;
    float* ZT    = wsf + WS_ZT;
    float* outp  = (float*)d_out;

    k_setup<<<512, 256, 0, stream>>>(Lambda_re, Lambda_im, p_re, p_im, q_re, q_im,
                                     Vc_re, Vc_im, Ct, Bv, log_step, terms);
    k_mainA<<<1024, 512, 0, stream>>>(terms, ZT);
    k_fftB<<<1024, 256, 0, stream>>>(ZT, outp);
}